// Round 1
// baseline (532.739 us; speedup 1.0000x reference)
//
#include <hip/hip_runtime.h>
#include <math.h>

// Problem: N=64, S=2048, D=768, fp32.
//   scores[n,s] = hidden[n,s,:] . w_att        (402.7 MB read -> must be single pass)
//   attn = softmax_s(scores)
//   cvec[n,:]  = sum_s attn[n,s] * hidden[n,s,:]
//   y_pred[n]  = sigmoid(cvec[n] . w_rec + b_rec)
//   ctx_pred[n]= sigmoid(cvec[n] . ctx[n,0,:])
// Output layout: [y_pred(64) | ctx_pred(64) | cvec(64*768)]
//
// Strategy: single fused pass over `hidden` with online softmax (flash-style).
// Each wave owns a strided set of tokens for one (n, partition); a token's 768
// floats live in registers for both the score dot and the weighted accumulate.

#define N_BATCH 64
#define S_LEN   2048
#define D_DIM   768
#define P_PART  32                         // S-partitions per batch row
#define TOK_PER_BLOCK (S_LEN / P_PART)     // 64
#define WAVES_PER_BLOCK 4
#define TOK_PER_WAVE (TOK_PER_BLOCK / WAVES_PER_BLOCK)  // 16
#define SLOT_F  772                        // per-partial: m, l, pad, pad, acc[768] (16B-aligned acc)

__global__ __launch_bounds__(256) void attn_pass1(
    const float* __restrict__ hidden,      // [N, S, D]
    const float* __restrict__ w_att,       // [D]
    float* __restrict__ ws)                // [N*P_PART, SLOT_F]
{
    const int blk  = blockIdx.x;           // n * P_PART + p
    const int n    = blk / P_PART;
    const int p    = blk % P_PART;
    const int tid  = threadIdx.x;
    const int wave = tid >> 6;
    const int lane = tid & 63;

    // Each lane owns 3 float4 slices of the D dimension: d4 = lane + 64*j
    const float4* wa4 = (const float4*)w_att;
    const float4 w0 = wa4[lane];
    const float4 w1 = wa4[lane + 64];
    const float4 w2 = wa4[lane + 128];

    float m = -1e30f, l = 0.f;
    float4 a0 = {0.f,0.f,0.f,0.f}, a1 = {0.f,0.f,0.f,0.f}, a2 = {0.f,0.f,0.f,0.f};

    const int s_base = p * TOK_PER_BLOCK + wave;   // tokens: s_base + 4*t

    for (int t = 0; t < TOK_PER_WAVE; ++t) {
        const int s = s_base + WAVES_PER_BLOCK * t;
        const float4* h4 = (const float4*)(hidden + ((size_t)n * S_LEN + s) * D_DIM);
        const float4 h0 = h4[lane];
        const float4 h1 = h4[lane + 64];
        const float4 h2 = h4[lane + 128];

        // per-lane partial dot, then 64-lane butterfly reduce (all lanes get score)
        float sc = h0.x*w0.x + h0.y*w0.y + h0.z*w0.z + h0.w*w0.w
                 + h1.x*w1.x + h1.y*w1.y + h1.z*w1.z + h1.w*w1.w
                 + h2.x*w2.x + h2.y*w2.y + h2.z*w2.z + h2.w*w2.w;
        #pragma unroll
        for (int off = 32; off; off >>= 1) sc += __shfl_xor(sc, off);

        // online softmax update (branch is wave-uniform)
        if (sc > m) {
            const float scale = __expf(m - sc);   // first iter: exp(-huge) -> 0
            l *= scale;
            a0.x *= scale; a0.y *= scale; a0.z *= scale; a0.w *= scale;
            a1.x *= scale; a1.y *= scale; a1.z *= scale; a1.w *= scale;
            a2.x *= scale; a2.y *= scale; a2.z *= scale; a2.w *= scale;
            m = sc;
        }
        const float pe = __expf(sc - m);
        l += pe;
        a0.x = fmaf(pe, h0.x, a0.x); a0.y = fmaf(pe, h0.y, a0.y);
        a0.z = fmaf(pe, h0.z, a0.z); a0.w = fmaf(pe, h0.w, a0.w);
        a1.x = fmaf(pe, h1.x, a1.x); a1.y = fmaf(pe, h1.y, a1.y);
        a1.z = fmaf(pe, h1.z, a1.z); a1.w = fmaf(pe, h1.w, a1.w);
        a2.x = fmaf(pe, h2.x, a2.x); a2.y = fmaf(pe, h2.y, a2.y);
        a2.z = fmaf(pe, h2.z, a2.z); a2.w = fmaf(pe, h2.w, a2.w);
    }

    // Block-level merge of the 4 wave partials via LDS.
    __shared__ float sm[WAVES_PER_BLOCK];
    __shared__ float sl[WAVES_PER_BLOCK];
    __shared__ float sacc[WAVES_PER_BLOCK][D_DIM];

    float4* my = (float4*)sacc[wave];
    my[lane]       = a0;
    my[lane + 64]  = a1;
    my[lane + 128] = a2;
    if (lane == 0) { sm[wave] = m; sl[wave] = l; }
    __syncthreads();

    const float mb = fmaxf(fmaxf(sm[0], sm[1]), fmaxf(sm[2], sm[3]));
    float e0 = __expf(sm[0] - mb), e1 = __expf(sm[1] - mb);
    float e2 = __expf(sm[2] - mb), e3 = __expf(sm[3] - mb);

    float* slot = ws + (size_t)blk * SLOT_F;
    #pragma unroll
    for (int k = 0; k < 3; ++k) {
        const int d = tid + 256 * k;
        const float v = sacc[0][d]*e0 + sacc[1][d]*e1 + sacc[2][d]*e2 + sacc[3][d]*e3;
        slot[4 + d] = v;                   // coalesced
    }
    if (tid == 0) {
        slot[0] = mb;
        slot[1] = sl[0]*e0 + sl[1]*e1 + sl[2]*e2 + sl[3]*e3;
    }
}

__global__ __launch_bounds__(256) void attn_pass2(
    const float* __restrict__ ws,          // [N*P_PART, SLOT_F]
    const float* __restrict__ ctx,         // [N, 1, D]
    const float* __restrict__ w_rec,       // [D]
    const float* __restrict__ b_rec,       // [1]
    float* __restrict__ out)               // [64 y | 64 ctx | 64*768 cvec]
{
    const int n   = blockIdx.x;
    const int tid = threadIdx.x;
    const float* base = ws + (size_t)n * P_PART * SLOT_F;

    // global max over partials (uniform scalar loads, broadcast)
    float mg = -1e30f;
    #pragma unroll
    for (int i = 0; i < P_PART; ++i) mg = fmaxf(mg, base[i * SLOT_F]);

    float ew[P_PART];
    float Lg = 0.f;
    #pragma unroll
    for (int i = 0; i < P_PART; ++i) {
        ew[i] = __expf(base[i * SLOT_F] - mg);
        Lg = fmaf(base[i * SLOT_F + 1], ew[i], Lg);
    }
    const float inv = 1.f / Lg;

    float py = 0.f, pc = 0.f;
    #pragma unroll
    for (int k = 0; k < 3; ++k) {
        const int d = tid + 256 * k;
        float v = 0.f;
        #pragma unroll
        for (int i = 0; i < P_PART; ++i)
            v = fmaf(base[i * SLOT_F + 4 + d], ew[i], v);   // coalesced across threads
        v *= inv;
        out[128 + n * D_DIM + d] = v;                        // cvec
        py = fmaf(v, w_rec[d], py);
        pc = fmaf(v, ctx[n * D_DIM + d], pc);
    }

    // block reduce the two dot products
    #pragma unroll
    for (int off = 32; off; off >>= 1) {
        py += __shfl_xor(py, off);
        pc += __shfl_xor(pc, off);
    }
    __shared__ float rs[8];
    if ((tid & 63) == 0) { rs[tid >> 6] = py; rs[4 + (tid >> 6)] = pc; }
    __syncthreads();
    if (tid == 0) {
        const float y = rs[0] + rs[1] + rs[2] + rs[3] + b_rec[0];
        const float c = rs[4] + rs[5] + rs[6] + rs[7];
        out[n]      = 1.f / (1.f + __expf(-y));
        out[64 + n] = 1.f / (1.f + __expf(-c));
    }
}

extern "C" void kernel_launch(void* const* d_in, const int* in_sizes, int n_in,
                              void* d_out, int out_size, void* d_ws, size_t ws_size,
                              hipStream_t stream) {
    const float* hidden = (const float*)d_in[0];
    const float* ctx    = (const float*)d_in[1];
    const float* w_att  = (const float*)d_in[2];
    const float* w_rec  = (const float*)d_in[3];
    const float* b_rec  = (const float*)d_in[4];
    float* out = (float*)d_out;
    float* ws  = (float*)d_ws;     // needs N*P_PART*SLOT_F*4 = 6.3 MB

    attn_pass1<<<N_BATCH * P_PART, 256, 0, stream>>>(hidden, w_att, ws);
    attn_pass2<<<N_BATCH, 256, 0, stream>>>(ws, ctx, w_rec, b_rec, out);
}